// Round 11
// baseline (26.777 us; speedup 1.0000x reference)
//
#include <hip/hip_runtime.h>
#include <hip/hip_bf16.h>

// Problem constants: B=8, G=2048, K=32, N=6, C=64; fourier_B is (7,32)
// out: (B, 128, G) float32
//
// Algebraic simplifications (validated):
//  1) up/down == mean_k(knn_f) since e_x is constant over k, so
//     kl_raw = 2*mean_k(sin^5/cos^5(2*pi*x)).
//  2) x = fB . [p, p x n, p.n] is linear in p:
//     x = e0*p0 + e1*p1 + e2*p2 with per-channel e precomputed from fB and n.
//
// Round 11: zero-LDS inner loop. lane = (half, channel jj); k is wave-uniform
// per iteration, so the per-k p-vector is broadcast from lane k's registers
// via v_readlane (no LDS pipe, no latency chain). Lanes 0-31 produce sin
// channels, 32-63 cos channels (shift=0.25 rev). Only the output tile klbuf
// stays in LDS for coalesced float4 stores.

#if __has_builtin(__builtin_amdgcn_fractf)
  #define FRACT(x) __builtin_amdgcn_fractf(x)
#else
  #define FRACT(x) ((x) - floorf(x))
#endif

__device__ __forceinline__ float rlanef(float v, int l) {
    return __int_as_float(__builtin_amdgcn_readlane(__float_as_int(v), l));
}

__global__ __launch_bounds__(256, 8) void line_pass1(
    const float* __restrict__ lc_x,     // (B,G,64)
    const float* __restrict__ knn_x,    // (B,G,32,6)
    const float* __restrict__ fB,       // (7,32)
    float* __restrict__ out)            // (B,128,G)
{
    const int wave = threadIdx.x >> 6;
    const int lane = threadIdx.x & 63;
    const int jj   = lane & 31;                 // channel (within half)
    // bijective XCD swizzle: 2048 blocks, 8 XCDs, 256 blocks each
    const int sbid = (blockIdx.x & 7) * 256 + (blockIdx.x >> 3);
    const int bg0  = sbid * 8;                  // 8 consecutive bg per block
    const int b    = bg0 >> 11;
    const int g0   = bg0 & 2047;                // 8-aligned, never crosses b

    __shared__ float klbuf[128][9];             // [channel][col], odd pad

    // fourier_B column for this lane's channel
    const float fb0 = fB[0*32 + jj];
    const float fb1 = fB[1*32 + jj];
    const float fb2 = fB[2*32 + jj];
    const float fb3 = fB[3*32 + jj];
    const float fb4 = fB[4*32 + jj];
    const float fb5 = fB[5*32 + jj];
    const float fb6 = fB[6*32 + jj];

    // lanes >= 32 compute cos channels: cos(2*pi*x) = sin(2*pi*(x+0.25))
    const float shift = (lane >= 32) ? 0.25f : 0.0f;

    #pragma unroll
    for (int i = 0; i < 2; ++i) {
        const int bg  = bg0 + wave * 2 + i;
        const int col = wave * 2 + i;

        // coalesced lc load; n = lc[3..5] via register broadcast
        const float myv = lc_x[(size_t)bg * 64 + lane];
        const float n0 = rlanef(myv, 3);
        const float n1 = rlanef(myv, 4);
        const float n2 = rlanef(myv, 5);

        // lc_line: normalize over C=64
        float ssum = myv * myv;
        #pragma unroll
        for (int off = 32; off; off >>= 1) ssum += __shfl_xor(ssum, off, 64);
        klbuf[64 + lane][col] = myv / sqrtf(ssum);

        // per-lane neighbor gather: lane l holds p(k = l&31)
        const float* kp = knn_x + (size_t)bg * 192 + jj * 6;
        const float p0 = kp[3];
        const float p1 = kp[4];
        const float p2 = kp[5];

        // effective projection vector: x = e0*p0 + e1*p1 + e2*p2
        const float e0 = fmaf(fb6, n0, fmaf(fb5,  n1, fmaf(fb4, -n2, fb0)));
        const float e1 = fmaf(fb6, n1, fmaf(fb5, -n0, fmaf(fb3,  n2, fb1)));
        const float e2 = fmaf(fb6, n2, fmaf(fb4,  n0, fmaf(fb3, -n1, fb2)));

        float a0 = 0.f, a1 = 0.f, a2 = 0.f, a3 = 0.f;
        #pragma unroll
        for (int t = 0; t < 32; ++t) {
            // k = t is wave-uniform: broadcast lane t's p via v_readlane
            const float sp0 = rlanef(p0, t);
            const float sp1 = rlanef(p1, t);
            const float sp2 = rlanef(p2, t);
            const float x  = fmaf(e2, sp2, fmaf(e1, sp1, e0 * sp0));
            const float tt = FRACT(x + shift);           // revolutions [0,1)
            const float s  = __builtin_amdgcn_sinf(tt);  // sin / cos channel
            const float s2 = s * s, s4 = s2 * s2;
            const float v  = s4 * s;                     // s^5
            switch (t & 3) {                             // 4 acc chains
                case 0: a0 += v; break;
                case 1: a1 += v; break;
                case 2: a2 += v; break;
                default: a3 += v; break;
            }
        }
        // kl_raw = 2 * mean_k = sum / 16
        klbuf[lane][col] = ((a0 + a1) + (a2 + a3)) * 0.0625f;
    }

    __syncthreads();

    // cooperative coalesced store: thread t -> row c=t>>1, cols (t&1)*4..+3
    const int c  = threadIdx.x >> 1;
    const int j0 = (threadIdx.x & 1) * 4;
    const float4 o = make_float4(klbuf[c][j0], klbuf[c][j0+1],
                                 klbuf[c][j0+2], klbuf[c][j0+3]);
    *(float4*)(out + ((size_t)b * 128 + c) * 2048 + g0 + j0) = o;
}

__global__ __launch_bounds__(256) void line_pass2(float* __restrict__ out)
{
    const int b = blockIdx.x >> 6;   // 0..7
    const int c = blockIdx.x & 63;   // 0..63
    float4*       kl = (float4*)(out + ((size_t)b * 128 + c) * 2048);
    const float4* ll = (const float4*)(out + ((size_t)b * 128 + 64 + c) * 2048);
    const int t = threadIdx.x;

    // issue ALL loads before the reduction so HBM latencies overlap
    const float4 v0 = kl[t];
    const float4 v1 = kl[t + 256];
    const float4 l0 = ll[t];
    const float4 l1 = ll[t + 256];

    float ss = v0.x*v0.x + v0.y*v0.y + v0.z*v0.z + v0.w*v0.w
             + v1.x*v1.x + v1.y*v1.y + v1.z*v1.z + v1.w*v1.w;
    #pragma unroll
    for (int off = 32; off; off >>= 1) ss += __shfl_xor(ss, off, 64);

    __shared__ float wsum[4];
    if ((t & 63) == 0) wsum[t >> 6] = ss;
    __syncthreads();
    const float tot = wsum[0] + wsum[1] + wsum[2] + wsum[3];
    const float rn  = 1.0f / sqrtf(tot);

    kl[t]       = make_float4(fmaf(v0.x, rn, -l0.x), fmaf(v0.y, rn, -l0.y),
                              fmaf(v0.z, rn, -l0.z), fmaf(v0.w, rn, -l0.w));
    kl[t + 256] = make_float4(fmaf(v1.x, rn, -l1.x), fmaf(v1.y, rn, -l1.y),
                              fmaf(v1.z, rn, -l1.z), fmaf(v1.w, rn, -l1.w));
}

extern "C" void kernel_launch(void* const* d_in, const int* in_sizes, int n_in,
                              void* d_out, int out_size, void* d_ws, size_t ws_size,
                              hipStream_t stream) {
    const float* lc_x  = (const float*)d_in[0];   // 8*2048*64
    const float* knn_x = (const float*)d_in[1];   // 8*2048*32*6
    const float* fB    = (const float*)d_in[2];   // 7*32
    float* out = (float*)d_out;                   // 8*128*2048

    line_pass1<<<2048, 256, 0, stream>>>(lc_x, knn_x, fB, out);
    line_pass2<<<512, 256, 0, stream>>>(out);
}